// Round 1
// 1025.903 us; speedup vs baseline: 1.5715x; 1.5715x over previous
//
#include <hip/hip_runtime.h>
#include <math.h>

// Problem constants
#define NQ 16384        // B*H*W = 16*32*32 query rows
#define DD 512          // feature dim
#define MM 2000         // memory slots
#define MPAD 2048       // padded memory slots (zero rows 2000..2047)
#define KPAD 2048       // padded K for gemm2 (zero cols 2000..2047)

// d_out layout (floats, concatenated in return order)
#define UQ_OFF   0            // updated_query  (16,1024,32,32) = 16777216
#define UM_OFF   16777216     // updated_memory (2000,512)      = 1024000
#define SQ_OFF   17801216     // score_query    (16384,2000)    = 32768000
#define SM_OFF   50569216     // score_memory   (16384,2000)    = 32768000
#define SEP_OFF  83337216     // separateness_loss scalar
#define COMP_OFF 83337217     // compactness_loss scalar

typedef unsigned short u16;
typedef __attribute__((ext_vector_type(8))) short bhalf8;   // 8 bf16 (4 VGPRs)
typedef __attribute__((ext_vector_type(4))) float f32x4;    // MFMA accumulator

// Static device workspace. All buffers fully (re)written every call before read,
// except the zero pads (rows/cols >= 2000) which rely on .bss zero-init and are
// never written by any kernel -> stay zero across calls.
__device__ float    g_qf[NQ * DD];        // normalized query rows (n,d) row-major
__device__ float    g_keyshat[MM * DD];   // unit-normalized keys (fp32, for rerank)
__device__ float    g_invn[NQ];           // 1/||query row||
__device__ int      g_top1[NQ];
__device__ int      g_top2[NQ];
__device__ unsigned g_colmax[MM];         // bits of max exp((s-1)*10) per column
__device__ float    g_colsum[MM];         // sum  exp((s-1)*10) per column
__device__ float    g_wraw[NQ];
__device__ float    g_denom[MM];          // segment sum of w_raw
__device__ float    g_bins[128];          // [0:64) separateness partials, [64:128) compactness
// CSR inversion of g = top1 mapping
__device__ int      g_cnt[MM];
__device__ int      g_cursor[MM];
__device__ int      g_base[MM];
__device__ int      g_rows[NQ];
__device__ float    g_wvals[NQ];

// split-bf16 operand buffers for the MFMA GEMMs
__device__ __attribute__((aligned(16))) u16 g_qh[NQ * DD];        // hi(qf)
__device__ __attribute__((aligned(16))) u16 g_ql[NQ * DD];        // lo(qf)
__device__ __attribute__((aligned(16))) u16 g_kh[MPAD * DD];      // hi(keys_hat), zero pad rows
__device__ __attribute__((aligned(16))) u16 g_kl[MPAD * DD];      // lo(keys_hat)
__device__ __attribute__((aligned(16))) u16 g_kth[DD * KPAD];     // hi(keys^T) raw keys, zero pad cols
__device__ __attribute__((aligned(16))) u16 g_ktl[DD * KPAD];     // lo(keys^T)
__device__ __attribute__((aligned(16))) u16 g_smh[(size_t)NQ * KPAD]; // hi(score_memory)
__device__ __attribute__((aligned(16))) u16 g_sml[(size_t)NQ * KPAD]; // lo(score_memory)

__device__ inline u16 f32_to_bf16(float x) {          // RNE truncation
    unsigned u = __float_as_uint(x);
    return (u16)((u + 0x7fffu + ((u >> 16) & 1u)) >> 16);
}
__device__ inline float bf16f(u16 h) { return __uint_as_float((unsigned)h << 16); }

// ---------------------------------------------------------------- init
__global__ __launch_bounds__(256) void init_kernel() {
    int i = blockIdx.x * 256 + threadIdx.x;
    if (i < MM) { g_colsum[i] = 0.f; g_denom[i] = 0.f; g_colmax[i] = 0u;
                  g_cnt[i] = 0; g_cursor[i] = 0; }
    if (i < 128) g_bins[i] = 0.f;
}

// ---------------------------------------------------------------- keys normalize (+ bf16 split)
__global__ __launch_bounds__(256) void keys_norm_kernel(const float* __restrict__ keys) {
    int m = blockIdx.x, t = threadIdx.x;
    float v0 = keys[m * DD + t], v1 = keys[m * DD + t + 256];
    __shared__ float red[256];
    red[t] = v0 * v0 + v1 * v1;
    __syncthreads();
    for (int s = 128; s > 0; s >>= 1) { if (t < s) red[t] += red[t + s]; __syncthreads(); }
    float inv = 1.f / fmaxf(sqrtf(red[0]), 1e-12f);
    float n0 = v0 * inv, n1 = v1 * inv;
    g_keyshat[m * DD + t]       = n0;
    g_keyshat[m * DD + t + 256] = n1;
    u16 h0 = f32_to_bf16(n0), h1 = f32_to_bf16(n1);
    g_kh[(size_t)m * DD + t]       = h0;
    g_kl[(size_t)m * DD + t]       = f32_to_bf16(n0 - bf16f(h0));
    g_kh[(size_t)m * DD + t + 256] = h1;
    g_kl[(size_t)m * DD + t + 256] = f32_to_bf16(n1 - bf16f(h1));
}

// ---------------------------------------------------------------- raw keys^T bf16 split (for gemm2 A)
__global__ __launch_bounds__(256) void ktrans_kernel(const float* __restrict__ keys) {
    __shared__ float tile[32][33];
    int tx = threadIdx.x & 31, ty = threadIdx.x >> 5;   // 8 rows of 32
    int c0 = blockIdx.x * 32;      // channel tile (512/32 = 16)
    int m0 = blockIdx.y * 32;      // memory tile (ceil(2000/32) = 63)
    for (int i = ty; i < 32; i += 8) {
        int m = m0 + i;
        tile[i][tx] = (m < MM) ? keys[(size_t)m * DD + c0 + tx] : 0.f;
    }
    __syncthreads();
    for (int i = ty; i < 32; i += 8) {
        int c = c0 + i;
        float v = tile[tx][i];
        u16 h = f32_to_bf16(v);
        g_kth[(size_t)c * KPAD + m0 + tx] = h;
        g_ktl[(size_t)c * KPAD + m0 + tx] = f32_to_bf16(v - bf16f(h));
    }
}

// ---------------------------------------------------------------- query normalize -> qf (n,d) + invn + bf16 split
__global__ __launch_bounds__(256) void qnorm_kernel(const float* __restrict__ q) {
    int bh = blockIdx.x; int b = bh >> 5, h = bh & 31;
    int t = threadIdx.x; int w = t & 31, dl = t >> 5;
    const float* qb = q + (size_t)b * DD * 1024 + h * 32;

    float ss = 0.f;
    for (int d = dl; d < DD; d += 8) { float v = qb[d * 1024 + w]; ss = fmaf(v, v, ss); }
    __shared__ float red[8][32];
    __shared__ float sinv[32];
    red[dl][w] = ss;
    __syncthreads();
    if (dl == 0) {
        float tot = 0.f;
        #pragma unroll
        for (int j = 0; j < 8; ++j) tot += red[j][w];
        float inv = 1.f / fmaxf(sqrtf(tot), 1e-12f);
        sinv[w] = inv;
        g_invn[b * 1024 + h * 32 + w] = inv;
    }
    __syncthreads();

    __shared__ float tile[32][33];
    int dcol = t & 31, wl = t >> 5;
    for (int d0 = 0; d0 < DD; d0 += 32) {
        for (int dd = dl; dd < 32; dd += 8)
            tile[dd][w] = qb[(d0 + dd) * 1024 + w] * sinv[w];
        __syncthreads();
        for (int wr = wl; wr < 32; wr += 8) {
            float v = tile[dcol][wr];
            size_t idx = ((size_t)b * 1024 + h * 32 + wr) * DD + d0 + dcol;
            g_qf[idx] = v;
            u16 hh = f32_to_bf16(v);
            g_qh[idx] = hh;
            g_ql[idx] = f32_to_bf16(v - bf16f(hh));
        }
        __syncthreads();
    }
}

// ---------------------------------------------------------------- updated_query first half
__global__ __launch_bounds__(256) void qf_out_kernel(const float* __restrict__ q, float* __restrict__ out) {
    int e0 = blockIdx.x * 1024 + threadIdx.x;
    #pragma unroll
    for (int i = 0; i < 4; ++i) {
        int e = e0 + i * 256;
        int b = e >> 19;
        int rem = e & ((1 << 19) - 1);
        int c = rem >> 10, r = rem & 1023;
        out[UQ_OFF + (size_t)(b * 1024 + c) * 1024 + r] = q[e] * g_invn[b * 1024 + r];
    }
}

// ---------------------------------------------------------------- shared MFMA inner block
// LDS tiles: [128 rows][64 k] u16, 16B slots XOR-swizzled by (row&7).
// Fragment k-map: within K32 sub-chunk, lane group hi=lane>>4 takes k = hi*8+j.
// Same map on A and B -> any internal HW k-permutation cancels (dot is k-symmetric).
__device__ inline void mfma_block(const u16 (*Ah)[64], const u16 (*Al)[64],
                                  const u16 (*Bh)[64], const u16 (*Bl)[64],
                                  int wr, int wc, int l15, int hi, f32x4 acc[4][4]) {
    for (int sub = 0; sub < 2; ++sub) {
        bhalf8 a_h[4], a_l[4], b_h[4], b_l[4];
        #pragma unroll
        for (int i = 0; i < 4; ++i) {
            int r = wr + i * 16 + l15;
            int ps = (((sub << 2) | hi) ^ (r & 7)) << 3;
            a_h[i] = *(const bhalf8*)&Ah[r][ps];
            a_l[i] = *(const bhalf8*)&Al[r][ps];
        }
        #pragma unroll
        for (int j = 0; j < 4; ++j) {
            int c = wc + j * 16 + l15;
            int ps = (((sub << 2) | hi) ^ (c & 7)) << 3;
            b_h[j] = *(const bhalf8*)&Bh[c][ps];
            b_l[j] = *(const bhalf8*)&Bl[c][ps];
        }
        #pragma unroll
        for (int i = 0; i < 4; ++i)
            #pragma unroll
            for (int j = 0; j < 4; ++j) {
                acc[i][j] = __builtin_amdgcn_mfma_f32_16x16x32_bf16(a_h[i], b_h[j], acc[i][j], 0, 0, 0);
                acc[i][j] = __builtin_amdgcn_mfma_f32_16x16x32_bf16(a_h[i], b_l[j], acc[i][j], 0, 0, 0);
                acc[i][j] = __builtin_amdgcn_mfma_f32_16x16x32_bf16(a_l[i], b_h[j], acc[i][j], 0, 0, 0);
            }
    }
}

// ---------------------------------------------------------------- GEMM1 (MFMA): raw score = qf @ keys_hat^T -> SQ slot
// split-bf16 3-term emulation: err ~ 3*2^-18 * ||a||*||b|| <= ~1e-5 worst case.
__global__ __launch_bounds__(256, 2) void gemm1_mfma(float* __restrict__ out) {
    __shared__ __attribute__((aligned(16))) u16 Ah[128][64];
    __shared__ __attribute__((aligned(16))) u16 Al[128][64];
    __shared__ __attribute__((aligned(16))) u16 Bh[128][64];
    __shared__ __attribute__((aligned(16))) u16 Bl[128][64];
    int t = threadIdx.x;
    int lane = t & 63, wid = t >> 6;
    int wr = (wid >> 1) << 6, wc = (wid & 1) << 6;   // 2x2 waves, 64x64 each
    int l15 = lane & 15, hi = lane >> 4;
    int row0 = blockIdx.x * 128;     // query rows n
    int col0 = blockIdx.y * 128;     // memory cols m (padded to 2048)

    f32x4 acc[4][4] = {};
    int sr = t >> 3, sslot = t & 7;

    for (int k0 = 0; k0 < DD; k0 += 64) {
        #pragma unroll
        for (int pass = 0; pass < 4; ++pass) {
            int r = sr + pass * 32;
            int ps = (sslot ^ (r & 7)) << 3;
            size_t ga = (size_t)(row0 + r) * DD + k0 + sslot * 8;
            size_t gb = (size_t)(col0 + r) * DD + k0 + sslot * 8;
            *(uint4*)&Ah[r][ps] = *(const uint4*)&g_qh[ga];
            *(uint4*)&Al[r][ps] = *(const uint4*)&g_ql[ga];
            *(uint4*)&Bh[r][ps] = *(const uint4*)&g_kh[gb];
            *(uint4*)&Bl[r][ps] = *(const uint4*)&g_kl[gb];
        }
        __syncthreads();
        mfma_block(Ah, Al, Bh, Bl, wr, wc, l15, hi, acc);
        __syncthreads();
    }
    // C/D layout (HW-verified): col = lane&15, row = (lane>>4)*4 + reg
    #pragma unroll
    for (int i = 0; i < 4; ++i) {
        int rbase = row0 + wr + i * 16 + hi * 4;
        #pragma unroll
        for (int j = 0; j < 4; ++j) {
            int c = col0 + wc + j * 16 + l15;
            if (c < MM) {
                #pragma unroll
                for (int q = 0; q < 4; ++q)
                    out[SQ_OFF + (size_t)(rbase + q) * MM + c] = acc[i][j][q];
            }
        }
    }
}

// ---------------------------------------------------------------- row softmax (temp .1) + top2 + SM bf16 split
__global__ __launch_bounds__(256) void row_softmax_kernel(float* __restrict__ out) {
    int n = blockIdx.x, t = threadIdx.x;
    __shared__ float buf[MM];
    __shared__ float rv[256], rv2[256];
    __shared__ int   ri[256], ri2[256];

    const float* raw = out + SQ_OFF + (size_t)n * MM;
    float v1 = -3.0e38f, v2 = -3.0e38f; int i1 = 0x7fffffff, i2 = 0x7fffffff;
    #pragma unroll
    for (int i = 0; i < 8; ++i) {
        int idx = i * 256 + t;
        if (idx < MM) {
            float v = raw[idx];
            buf[idx] = v;
            if (v > v1)      { v2 = v1; i2 = i1; v1 = v; i1 = idx; }
            else if (v > v2) { v2 = v; i2 = idx; }
        }
    }
    rv[t] = v1; ri[t] = i1; rv2[t] = v2; ri2[t] = i2;
    __syncthreads();
    for (int s = 128; s > 0; s >>= 1) {
        if (t < s) {
            float av1 = rv[t],  bv1 = rv[t + s];
            float av2 = rv2[t], bv2 = rv2[t + s];
            int   ai1 = ri[t],  bi1 = ri[t + s];
            int   ai2 = ri2[t], bi2 = ri2[t + s];
            bool afirst = (av1 > bv1) || (av1 == bv1 && ai1 < bi1);
            float nv1, nv2; int ni1, ni2;
            if (afirst) {
                nv1 = av1; ni1 = ai1;
                if ((av2 > bv1) || (av2 == bv1 && ai2 < bi1)) { nv2 = av2; ni2 = ai2; }
                else                                          { nv2 = bv1; ni2 = bi1; }
            } else {
                nv1 = bv1; ni1 = bi1;
                if ((bv2 > av1) || (bv2 == av1 && bi2 < ai1)) { nv2 = bv2; ni2 = bi2; }
                else                                          { nv2 = av1; ni2 = ai1; }
            }
            rv[t] = nv1; ri[t] = ni1; rv2[t] = nv2; ri2[t] = ni2;
        }
        __syncthreads();
    }
    float rowmax = rv[0];
    if (t == 0) { g_top1[n] = ri[0]; g_top2[n] = ri2[0]; }
    __syncthreads();

    float lsum = 0.f;
    #pragma unroll
    for (int i = 0; i < 8; ++i) {
        int idx = i * 256 + t;
        if (idx < MM) {
            float e = expf((buf[idx] - rowmax) * 10.0f);
            buf[idx] = e;
            lsum += e;
        }
    }
    rv[t] = lsum;
    __syncthreads();
    for (int s = 128; s > 0; s >>= 1) { if (t < s) rv[t] += rv[t + s]; __syncthreads(); }
    float inv = 1.f / rv[0];
    float* sm = out + SM_OFF + (size_t)n * MM;
    #pragma unroll
    for (int i = 0; i < 8; ++i) {
        int idx = i * 256 + t;
        if (idx < MM) {
            float smv = buf[idx] * inv;
            sm[idx] = smv;
            u16 hh = f32_to_bf16(smv);
            g_smh[(size_t)n * KPAD + idx] = hh;
            g_sml[(size_t)n * KPAD + idx] = f32_to_bf16(smv - bf16f(hh));
        }
    }
}

// ---------------------------------------------------------------- fp32 rerank of top1/top2 (one wave per row)
// Restores top-k decisions to fp32 fidelity after split-bf16 scoring.
__global__ __launch_bounds__(256) void rerank_kernel() {
    int n = blockIdx.x * 4 + (threadIdx.x >> 6);
    int lane = threadIdx.x & 63;
    int i1 = g_top1[n], i2 = g_top2[n];
    const float* q  = g_qf      + (size_t)n  * DD;
    const float* k1 = g_keyshat + (size_t)i1 * DD;
    const float* k2 = g_keyshat + (size_t)i2 * DD;
    float s1 = 0.f, s2 = 0.f;
    for (int k = lane; k < DD; k += 64) {
        float qv = q[k];
        s1 = fmaf(qv, k1[k], s1);
        s2 = fmaf(qv, k2[k], s2);
    }
    #pragma unroll
    for (int off = 32; off > 0; off >>= 1) {
        s1 += __shfl_down(s1, off);
        s2 += __shfl_down(s2, off);
    }
    if (lane == 0) {
        if (s2 > s1 || (s2 == s1 && i2 < i1)) { g_top1[n] = i2; g_top2[n] = i1; }
    }
}

// ---------------------------------------------------------------- column stats: max & sum of exp((s-1)*10)
__global__ __launch_bounds__(256) void col_stats_kernel(const float* __restrict__ out) {
    int m = blockIdx.x * 256 + threadIdx.x;
    if (m >= MM) return;
    int n0 = blockIdx.y * 256;
    const float* raw = out + SQ_OFF;
    float lmax = 0.f, lsum = 0.f;
    for (int i = 0; i < 256; ++i) {
        float v = raw[(size_t)(n0 + i) * MM + m];
        float e = expf((v - 1.0f) * 10.0f);
        lmax = fmaxf(lmax, e);
        lsum += e;
    }
    atomicMax(&g_colmax[m], __float_as_uint(lmax));
    atomicAdd(&g_colsum[m], lsum);
}

// ---------------------------------------------------------------- score_query = exp((s-1)*10)/colsum
__global__ __launch_bounds__(256) void score_query_kernel(float* __restrict__ out) {
    int m = blockIdx.x * 256 + threadIdx.x;
    if (m >= MM) return;
    int n0 = blockIdx.y * 8;
    float inv = 1.f / g_colsum[m];
    float* raw = out + SQ_OFF;
    #pragma unroll
    for (int i = 0; i < 8; ++i) {
        size_t idx = (size_t)(n0 + i) * MM + m;
        raw[idx] = expf((raw[idx] - 1.0f) * 10.0f) * inv;
    }
}

// ---------------------------------------------------------------- w_raw + denom + per-slot counts
__global__ __launch_bounds__(256) void wraw_kernel(const float* __restrict__ out) {
    int n = blockIdx.x * 256 + threadIdx.x;
    int gi = g_top1[n];
    float sqv = out[SQ_OFF + (size_t)n * MM + gi];
    float cm = __uint_as_float(g_colmax[gi]) / g_colsum[gi];
    float w = sqv / (cm + 1e-8f);
    g_wraw[n] = w;
    atomicAdd(&g_denom[gi], w);
    atomicAdd(&g_cnt[gi], 1);
}

// ---------------------------------------------------------------- exclusive scan of g_cnt -> g_base (1 block)
__global__ __launch_bounds__(256) void scan_kernel() {
    int t = threadIdx.x;
    __shared__ int chunk[256];
    __shared__ int off[256];
    int loc[8];
    int s = 0;
    #pragma unroll
    for (int i = 0; i < 8; ++i) {
        int idx = t * 8 + i;
        int c = (idx < MM) ? g_cnt[idx] : 0;
        loc[i] = s; s += c;
    }
    chunk[t] = s;
    __syncthreads();
    if (t == 0) {
        int acc = 0;
        for (int i = 0; i < 256; ++i) { off[i] = acc; acc += chunk[i]; }
    }
    __syncthreads();
    #pragma unroll
    for (int i = 0; i < 8; ++i) {
        int idx = t * 8 + i;
        if (idx < MM) g_base[idx] = off[t] + loc[i];
    }
}

// ---------------------------------------------------------------- scatter rows into CSR
__global__ __launch_bounds__(256) void scatter_kernel() {
    int n = blockIdx.x * 256 + threadIdx.x;
    int gi = g_top1[n];
    int pos = atomicAdd(&g_cursor[gi], 1);
    int dst = g_base[gi] + pos;
    g_rows[dst]  = n;
    g_wvals[dst] = g_wraw[n];
}

// ---------------------------------------------------------------- updated_memory via CSR lists
__global__ __launch_bounds__(256) void seg_update_kernel(const float* __restrict__ keys, float* __restrict__ out) {
    int m = blockIdx.x, t = threadIdx.x;
    int start = g_base[m], cnt = g_cnt[m];
    float invd = 1.f / (g_denom[m] + 1e-8f);
    float acc0 = 0.f, acc1 = 0.f;
    for (int i = 0; i < cnt; ++i) {
        int   row = g_rows[start + i];       // block-uniform -> L1 broadcast
        float wgt = g_wvals[start + i] * invd;
        acc0 = fmaf(wgt, g_qf[(size_t)row * DD + t],       acc0);
        acc1 = fmaf(wgt, g_qf[(size_t)row * DD + t + 256], acc1);
    }
    float v0 = acc0 + keys[m * DD + t];
    float v1 = acc1 + keys[m * DD + t + 256];
    __shared__ float red[256];
    red[t] = v0 * v0 + v1 * v1;
    __syncthreads();
    for (int s = 128; s > 0; s >>= 1) { if (t < s) red[t] += red[t + s]; __syncthreads(); }
    float inv = 1.f / fmaxf(sqrtf(red[0]), 1e-12f);
    out[UM_OFF + (size_t)m * DD + t]       = v0 * inv;
    out[UM_OFF + (size_t)m * DD + t + 256] = v1 * inv;
}

// ---------------------------------------------------------------- GEMM2 (MFMA): (SM @ keys)^T via A=keys^T, B=SM
// D[channel][n]; coalesced float stores into UQ second half.
__global__ __launch_bounds__(256, 2) void gemm2_mfma(float* __restrict__ out) {
    __shared__ __attribute__((aligned(16))) u16 Ah[128][64];
    __shared__ __attribute__((aligned(16))) u16 Al[128][64];
    __shared__ __attribute__((aligned(16))) u16 Bh[128][64];
    __shared__ __attribute__((aligned(16))) u16 Bl[128][64];
    int t = threadIdx.x;
    int lane = t & 63, wid = t >> 6;
    int wr = (wid >> 1) << 6, wc = (wid & 1) << 6;
    int l15 = lane & 15, hi = lane >> 4;
    int row0 = blockIdx.x * 128;     // channel dim (0..511)
    int col0 = blockIdx.y * 128;     // query rows n

    f32x4 acc[4][4] = {};
    int sr = t >> 3, sslot = t & 7;

    for (int k0 = 0; k0 < KPAD; k0 += 64) {
        #pragma unroll
        for (int pass = 0; pass < 4; ++pass) {
            int r = sr + pass * 32;
            int ps = (sslot ^ (r & 7)) << 3;
            size_t ga = (size_t)(row0 + r) * KPAD + k0 + sslot * 8;
            size_t gb = (size_t)(col0 + r) * KPAD + k0 + sslot * 8;
            *(uint4*)&Ah[r][ps] = *(const uint4*)&g_kth[ga];
            *(uint4*)&Al[r][ps] = *(const uint4*)&g_ktl[ga];
            *(uint4*)&Bh[r][ps] = *(const uint4*)&g_smh[gb];
            *(uint4*)&Bl[r][ps] = *(const uint4*)&g_sml[gb];
        }
        __syncthreads();
        mfma_block(Ah, Al, Bh, Bl, wr, wc, l15, hi, acc);
        __syncthreads();
    }
    int bq = col0 >> 10;
    #pragma unroll
    for (int i = 0; i < 4; ++i) {
        int chb = row0 + wr + i * 16 + hi * 4;
        #pragma unroll
        for (int j = 0; j < 4; ++j) {
            int n = col0 + wc + j * 16 + l15;
            size_t base = UQ_OFF + ((size_t)(bq * 1024 + 512 + chb)) * 1024 + (n & 1023);
            #pragma unroll
            for (int q = 0; q < 4; ++q)
                out[base + (size_t)q * 1024] = acc[i][j][q];
        }
    }
}

// ---------------------------------------------------------------- losses
__global__ __launch_bounds__(256) void loss_kernel(const float* __restrict__ keys) {
    int n = blockIdx.x, t = threadIdx.x;
    int gi = g_top1[n], ni = g_top2[n];
    float q0 = g_qf[(size_t)n * DD + t],      q1 = g_qf[(size_t)n * DD + t + 256];
    float p0 = keys[gi * DD + t],             p1 = keys[gi * DD + t + 256];
    float e0 = keys[ni * DD + t],             e1 = keys[ni * DD + t + 256];
    float dq0 = q0 - p0, dq1 = q1 - p1;
    float comp = dq0 * dq0 + dq1 * dq1;
    float a0 = dq0 + 1e-6f, a1 = dq1 + 1e-6f;
    float dpp = a0 * a0 + a1 * a1;
    float b0 = q0 - e0 + 1e-6f, b1 = q1 - e1 + 1e-6f;
    float dnn = b0 * b0 + b1 * b1;
    __shared__ float r1[256], r2[256], r3[256];
    r1[t] = comp; r2[t] = dpp; r3[t] = dnn;
    __syncthreads();
    for (int s = 128; s > 0; s >>= 1) {
        if (t < s) { r1[t] += r1[t + s]; r2[t] += r2[t + s]; r3[t] += r3[t + s]; }
        __syncthreads();
    }
    if (t == 0) {
        float dp = sqrtf(r2[0]), dn = sqrtf(r3[0]);
        float sep = fmaxf(dp - dn + 1.0f, 0.0f);
        atomicAdd(&g_bins[n & 63], sep);
        atomicAdd(&g_bins[64 + (n & 63)], r1[0]);
    }
}

__global__ __launch_bounds__(64) void finalize_kernel(float* __restrict__ out) {
    if (threadIdx.x == 0) {
        float s = 0.f, c = 0.f;
        for (int i = 0; i < 64; ++i) { s += g_bins[i]; c += g_bins[64 + i]; }
        out[SEP_OFF]  = s / (float)NQ;
        out[COMP_OFF] = c / ((float)NQ * (float)DD);
    }
}

// ---------------------------------------------------------------- launch
extern "C" void kernel_launch(void* const* d_in, const int* in_sizes, int n_in,
                              void* d_out, int out_size, void* d_ws, size_t ws_size,
                              hipStream_t stream) {
    const float* query = (const float*)d_in[0];
    const float* keys  = (const float*)d_in[1];
    float* out = (float*)d_out;

    init_kernel<<<dim3(8), dim3(256), 0, stream>>>();
    keys_norm_kernel<<<dim3(MM), dim3(256), 0, stream>>>(keys);
    ktrans_kernel<<<dim3(16, 63), dim3(256), 0, stream>>>(keys);
    qnorm_kernel<<<dim3(512), dim3(256), 0, stream>>>(query);
    qf_out_kernel<<<dim3(8192), dim3(256), 0, stream>>>(query, out);
    gemm1_mfma<<<dim3(128, 16), dim3(256), 0, stream>>>(out);
    row_softmax_kernel<<<dim3(NQ), dim3(256), 0, stream>>>(out);
    rerank_kernel<<<dim3(NQ / 4), dim3(256), 0, stream>>>();
    col_stats_kernel<<<dim3(8, 64), dim3(256), 0, stream>>>(out);
    score_query_kernel<<<dim3(8, 2048), dim3(256), 0, stream>>>(out);
    wraw_kernel<<<dim3(64), dim3(256), 0, stream>>>(out);
    scan_kernel<<<dim3(1), dim3(256), 0, stream>>>();
    scatter_kernel<<<dim3(64), dim3(256), 0, stream>>>();
    seg_update_kernel<<<dim3(MM), dim3(256), 0, stream>>>(keys, out);
    gemm2_mfma<<<dim3(4, 128), dim3(256), 0, stream>>>(out);
    loss_kernel<<<dim3(NQ), dim3(256), 0, stream>>>(keys);
    finalize_kernel<<<dim3(1), dim3(64), 0, stream>>>(out);
}

// Round 2
// 971.885 us; speedup vs baseline: 1.6588x; 1.0556x over previous
//
#include <hip/hip_runtime.h>
#include <math.h>

// Problem constants
#define NQ 16384        // B*H*W = 16*32*32 query rows
#define DD 512          // feature dim
#define MM 2000         // memory slots
#define MPAD 2048       // padded memory slots (zero rows 2000..2047)
#define KPAD 2048       // padded K for gemm2 (zero cols 2000..2047)

// d_out layout (floats, concatenated in return order)
#define UQ_OFF   0            // updated_query  (16,1024,32,32) = 16777216
#define UM_OFF   16777216     // updated_memory (2000,512)      = 1024000
#define SQ_OFF   17801216     // score_query    (16384,2000)    = 32768000
#define SM_OFF   50569216     // score_memory   (16384,2000)    = 32768000
#define SEP_OFF  83337216     // separateness_loss scalar
#define COMP_OFF 83337217     // compactness_loss scalar

typedef unsigned short u16;
typedef __attribute__((ext_vector_type(8))) short bhalf8;   // 8 bf16 (4 VGPRs)
typedef __attribute__((ext_vector_type(4))) float f32x4;    // MFMA accumulator

// Static device workspace. All buffers fully (re)written every call before read,
// except the zero pads (rows/cols >= 2000) which rely on .bss zero-init and are
// never written by any kernel -> stay zero across calls.
__device__ float    g_qf[NQ * DD];        // normalized query rows (n,d) row-major
__device__ float    g_keyshat[MM * DD];   // unit-normalized keys (fp32, for rerank)
__device__ int      g_top1[NQ];
__device__ int      g_top2[NQ];
__device__ unsigned g_colmax[MM];         // bits of max E per column
__device__ float    g_colsum[MM];         // sum  E per column
__device__ float    g_rowsum[NQ];         // sum  E per row
__device__ float    g_wraw[NQ];
__device__ float    g_denom[MM];          // segment sum of w_raw
__device__ float    g_bins[128];          // [0:64) separateness partials, [64:128) compactness
// CSR inversion of g = top1 mapping
__device__ int      g_cnt[MM];
__device__ int      g_cursor[MM];
__device__ int      g_base[MM];
__device__ int      g_rows[NQ];
__device__ float    g_wvals[NQ];

// split-bf16 operand buffers for the MFMA GEMMs
__device__ __attribute__((aligned(16))) u16 g_qh[NQ * DD];        // hi(qf)
__device__ __attribute__((aligned(16))) u16 g_ql[NQ * DD];        // lo(qf)
__device__ __attribute__((aligned(16))) u16 g_kh[MPAD * DD];      // hi(keys_hat), zero pad rows
__device__ __attribute__((aligned(16))) u16 g_kl[MPAD * DD];      // lo(keys_hat)
__device__ __attribute__((aligned(16))) u16 g_kth[DD * KPAD];     // hi(keys^T) raw keys, zero pad cols
__device__ __attribute__((aligned(16))) u16 g_ktl[DD * KPAD];     // lo(keys^T)
__device__ __attribute__((aligned(16))) u16 g_smh[(size_t)NQ * KPAD]; // hi(score_memory)
__device__ __attribute__((aligned(16))) u16 g_sml[(size_t)NQ * KPAD]; // lo(score_memory)

__device__ inline u16 f32_to_bf16(float x) {          // RNE
    unsigned u = __float_as_uint(x);
    return (u16)((u + 0x7fffu + ((u >> 16) & 1u)) >> 16);
}
__device__ inline float bf16f(u16 h) { return __uint_as_float((unsigned)h << 16); }

// async global->LDS, 16B per lane. Dest must be wave-uniform base (+lane*16 by HW).
__device__ __forceinline__ void gl_lds16(const void* g, void* l) {
    __builtin_amdgcn_global_load_lds(
        (const __attribute__((address_space(1))) void*)g,
        (__attribute__((address_space(3))) void*)l, 16, 0, 0);
}

// ---------------------------------------------------------------- init
__global__ __launch_bounds__(256) void init_kernel() {
    int i = blockIdx.x * 256 + threadIdx.x;
    if (i < MM) { g_colsum[i] = 0.f; g_denom[i] = 0.f; g_colmax[i] = 0u;
                  g_cnt[i] = 0; g_cursor[i] = 0; }
    if (i < 128) g_bins[i] = 0.f;
    if (i < NQ) g_rowsum[i] = 0.f;
}

// ---------------------------------------------------------------- keys normalize (+ bf16 split)
__global__ __launch_bounds__(256) void keys_norm_kernel(const float* __restrict__ keys) {
    int m = blockIdx.x, t = threadIdx.x;
    float v0 = keys[m * DD + t], v1 = keys[m * DD + t + 256];
    __shared__ float red[256];
    red[t] = v0 * v0 + v1 * v1;
    __syncthreads();
    for (int s = 128; s > 0; s >>= 1) { if (t < s) red[t] += red[t + s]; __syncthreads(); }
    float inv = 1.f / fmaxf(sqrtf(red[0]), 1e-12f);
    float n0 = v0 * inv, n1 = v1 * inv;
    g_keyshat[m * DD + t]       = n0;
    g_keyshat[m * DD + t + 256] = n1;
    u16 h0 = f32_to_bf16(n0), h1 = f32_to_bf16(n1);
    g_kh[(size_t)m * DD + t]       = h0;
    g_kl[(size_t)m * DD + t]       = f32_to_bf16(n0 - bf16f(h0));
    g_kh[(size_t)m * DD + t + 256] = h1;
    g_kl[(size_t)m * DD + t + 256] = f32_to_bf16(n1 - bf16f(h1));
}

// ---------------------------------------------------------------- raw keys^T bf16 split (for gemm2 A)
__global__ __launch_bounds__(256) void ktrans_kernel(const float* __restrict__ keys) {
    __shared__ float tile[32][33];
    int tx = threadIdx.x & 31, ty = threadIdx.x >> 5;   // 8 rows of 32
    int c0 = blockIdx.x * 32;      // channel tile (512/32 = 16)
    int m0 = blockIdx.y * 32;      // memory tile (ceil(2000/32) = 63)
    for (int i = ty; i < 32; i += 8) {
        int m = m0 + i;
        tile[i][tx] = (m < MM) ? keys[(size_t)m * DD + c0 + tx] : 0.f;
    }
    __syncthreads();
    for (int i = ty; i < 32; i += 8) {
        int c = c0 + i;
        float v = tile[tx][i];
        u16 h = f32_to_bf16(v);
        g_kth[(size_t)c * KPAD + m0 + tx] = h;
        g_ktl[(size_t)c * KPAD + m0 + tx] = f32_to_bf16(v - bf16f(h));
    }
}

// ---------------------------------------------------------------- query normalize -> qf + splits + UQ first half
__global__ __launch_bounds__(256) void qnorm_kernel(const float* __restrict__ q, float* __restrict__ out) {
    int bh = blockIdx.x; int b = bh >> 5, h = bh & 31;
    int t = threadIdx.x; int w = t & 31, dl = t >> 5;
    const float* qb = q + (size_t)b * DD * 1024 + h * 32;

    float ss = 0.f;
    for (int d = dl; d < DD; d += 8) { float v = qb[d * 1024 + w]; ss = fmaf(v, v, ss); }
    __shared__ float red[8][32];
    __shared__ float sinv[32];
    red[dl][w] = ss;
    __syncthreads();
    if (dl == 0) {
        float tot = 0.f;
        #pragma unroll
        for (int j = 0; j < 8; ++j) tot += red[j][w];
        sinv[w] = 1.f / fmaxf(sqrtf(tot), 1e-12f);
    }
    __syncthreads();

    __shared__ float tile[32][33];
    int dcol = t & 31, wl = t >> 5;
    for (int d0 = 0; d0 < DD; d0 += 32) {
        for (int dd = dl; dd < 32; dd += 8) {
            float v = qb[(d0 + dd) * 1024 + w] * sinv[w];
            tile[dd][w] = v;
            // fused updated_query first half: out[(b,channel,d0+dd, r=h*32+w)]
            out[UQ_OFF + (size_t)((b << 10) + d0 + dd) * 1024 + (h << 5) + w] = v;
        }
        __syncthreads();
        for (int wr = wl; wr < 32; wr += 8) {
            float v = tile[dcol][wr];
            size_t idx = ((size_t)b * 1024 + h * 32 + wr) * DD + d0 + dcol;
            g_qf[idx] = v;
            u16 hh = f32_to_bf16(v);
            g_qh[idx] = hh;
            g_ql[idx] = f32_to_bf16(v - bf16f(hh));
        }
        __syncthreads();
    }
}

// ---------------------------------------------------------------- shared MFMA inner block
// LDS tiles: [128 rows][64 k] u16, 16B slots XOR-swizzled by (row&7) (content: slot s holds global slot s^(r&7)).
__device__ inline void mfma_block(const u16 (*Ah)[64], const u16 (*Al)[64],
                                  const u16 (*Bh)[64], const u16 (*Bl)[64],
                                  int wr, int wc, int l15, int hi, f32x4 acc[4][4]) {
    for (int sub = 0; sub < 2; ++sub) {
        bhalf8 a_h[4], a_l[4], b_h[4], b_l[4];
        #pragma unroll
        for (int i = 0; i < 4; ++i) {
            int r = wr + i * 16 + l15;
            int ps = (((sub << 2) | hi) ^ (r & 7)) << 3;
            a_h[i] = *(const bhalf8*)&Ah[r][ps];
            a_l[i] = *(const bhalf8*)&Al[r][ps];
        }
        #pragma unroll
        for (int j = 0; j < 4; ++j) {
            int c = wc + j * 16 + l15;
            int ps = (((sub << 2) | hi) ^ (c & 7)) << 3;
            b_h[j] = *(const bhalf8*)&Bh[c][ps];
            b_l[j] = *(const bhalf8*)&Bl[c][ps];
        }
        #pragma unroll
        for (int i = 0; i < 4; ++i)
            #pragma unroll
            for (int j = 0; j < 4; ++j) {
                acc[i][j] = __builtin_amdgcn_mfma_f32_16x16x32_bf16(a_h[i], b_h[j], acc[i][j], 0, 0, 0);
                acc[i][j] = __builtin_amdgcn_mfma_f32_16x16x32_bf16(a_h[i], b_l[j], acc[i][j], 0, 0, 0);
                acc[i][j] = __builtin_amdgcn_mfma_f32_16x16x32_bf16(a_l[i], b_h[j], acc[i][j], 0, 0, 0);
            }
    }
}

// ---------------------------------------------------------------- GEMM1 (MFMA): E = exp((qf@keys_hat^T - 1)*10)
// Writes E to SQ slot; accumulates rowsum/colsum/colmax of E via atomics.
__global__ __launch_bounds__(256, 2) void gemm1_mfma(float* __restrict__ out) {
    __shared__ __attribute__((aligned(16))) u16 Ah[128][64];
    __shared__ __attribute__((aligned(16))) u16 Al[128][64];
    __shared__ __attribute__((aligned(16))) u16 Bh[128][64];
    __shared__ __attribute__((aligned(16))) u16 Bl[128][64];
    int t = threadIdx.x;
    int lane = t & 63, wv = t >> 6;
    int wr = (wv >> 1) << 6, wc = (wv & 1) << 6;   // 2x2 waves, 64x64 each
    int l15 = lane & 15, hi = lane >> 4;
    int row0 = blockIdx.x * 128;     // query rows n
    int col0 = blockIdx.y * 128;     // memory cols m (padded to 2048)

    f32x4 acc[4][4] = {};
    int lr = lane >> 3, sslot = lane & 7;
    int xs = sslot ^ lr;             // pre-swizzled source slot (XOR involution)

    for (int k0 = 0; k0 < DD; k0 += 64) {
        #pragma unroll
        for (int p = 0; p < 4; ++p) {
            int r = wv * 8 + lr + p * 32;
            size_t ga = (size_t)(row0 + r) * DD + k0 + xs * 8;
            size_t gb = (size_t)(col0 + r) * DD + k0 + xs * 8;
            gl_lds16(g_qh + ga, &Ah[p * 32 + wv * 8][0]);
            gl_lds16(g_ql + ga, &Al[p * 32 + wv * 8][0]);
            gl_lds16(g_kh + gb, &Bh[p * 32 + wv * 8][0]);
            gl_lds16(g_kl + gb, &Bl[p * 32 + wv * 8][0]);
        }
        __syncthreads();
        mfma_block(Ah, Al, Bh, Bl, wr, wc, l15, hi, acc);
        __syncthreads();
    }

    // Epilogue: E + store + row/col stats. C/D layout: col=lane&15, row=(lane>>4)*4+reg.
    float rowp[4][4];
    #pragma unroll
    for (int i = 0; i < 4; ++i)
        #pragma unroll
        for (int q = 0; q < 4; ++q) rowp[i][q] = 0.f;

    #pragma unroll
    for (int j = 0; j < 4; ++j) {
        int c = col0 + wc + j * 16 + l15;
        bool valid = (c < MM);                 // MM%16==0 -> uniform per 16-lane group
        float cs = 0.f, cm = 0.f;
        #pragma unroll
        for (int i = 0; i < 4; ++i) {
            int rbase = row0 + wr + i * 16 + hi * 4;
            #pragma unroll
            for (int q = 0; q < 4; ++q) {
                float e = __expf((acc[i][j][q] - 1.0f) * 10.0f);
                if (valid) out[SQ_OFF + (size_t)(rbase + q) * MM + c] = e;
                float ev = valid ? e : 0.f;
                rowp[i][q] += ev;
                cs += ev;
                cm = fmaxf(cm, ev);
            }
        }
        cs += __shfl_xor(cs, 16); cs += __shfl_xor(cs, 32);
        cm = fmaxf(cm, __shfl_xor(cm, 16)); cm = fmaxf(cm, __shfl_xor(cm, 32));
        if (hi == 0 && valid) {
            atomicAdd(&g_colsum[c], cs);
            atomicMax(&g_colmax[c], __float_as_uint(cm));
        }
    }
    #pragma unroll
    for (int i = 0; i < 4; ++i)
        #pragma unroll
        for (int q = 0; q < 4; ++q) {
            float v = rowp[i][q];
            v += __shfl_xor(v, 1); v += __shfl_xor(v, 2);
            v += __shfl_xor(v, 4); v += __shfl_xor(v, 8);
            if (l15 == 0) atomicAdd(&g_rowsum[row0 + wr + i * 16 + hi * 4 + q], v);
        }
}

// ---------------------------------------------------------------- row pass: top2 + SM + SQ finalize (single pass)
__global__ __launch_bounds__(256) void rowpass_kernel(float* __restrict__ out) {
    int n = blockIdx.x, t = threadIdx.x;
    __shared__ float rv[256], rv2[256];
    __shared__ int   ri[256], ri2[256];
    float inv_rs = 1.f / g_rowsum[n];
    float* raw = out + SQ_OFF + (size_t)n * MM;   // holds E
    float* sm  = out + SM_OFF + (size_t)n * MM;
    float v1 = -1.f, v2 = -1.f; int i1 = 0x7fffffff, i2 = 0x7fffffff;
    #pragma unroll
    for (int i = 0; i < 8; ++i) {
        int idx = i * 256 + t;
        if (idx < MM) {
            float e = raw[idx];
            if (e > v1)      { v2 = v1; i2 = i1; v1 = e; i1 = idx; }
            else if (e > v2) { v2 = e; i2 = idx; }
            float smv = e * inv_rs;               // softmax row: E/sum(E) (shift cancels)
            sm[idx] = smv;
            u16 hh = f32_to_bf16(smv);
            g_smh[(size_t)n * KPAD + idx] = hh;
            g_sml[(size_t)n * KPAD + idx] = f32_to_bf16(smv - bf16f(hh));
            raw[idx] = e / g_colsum[idx];         // score_query finalize in place
        }
    }
    rv[t] = v1; ri[t] = i1; rv2[t] = v2; ri2[t] = i2;
    __syncthreads();
    for (int s = 128; s > 0; s >>= 1) {
        if (t < s) {
            float av1 = rv[t],  bv1 = rv[t + s];
            float av2 = rv2[t], bv2 = rv2[t + s];
            int   ai1 = ri[t],  bi1 = ri[t + s];
            int   ai2 = ri2[t], bi2 = ri2[t + s];
            bool afirst = (av1 > bv1) || (av1 == bv1 && ai1 < bi1);
            float nv1, nv2; int ni1, ni2;
            if (afirst) {
                nv1 = av1; ni1 = ai1;
                if ((av2 > bv1) || (av2 == bv1 && ai2 < bi1)) { nv2 = av2; ni2 = ai2; }
                else                                          { nv2 = bv1; ni2 = bi1; }
            } else {
                nv1 = bv1; ni1 = bi1;
                if ((bv2 > av1) || (bv2 == av1 && bi2 < ai1)) { nv2 = bv2; ni2 = bi2; }
                else                                          { nv2 = av1; ni2 = ai1; }
            }
            rv[t] = nv1; ri[t] = ni1; rv2[t] = nv2; ri2[t] = ni2;
        }
        __syncthreads();
    }
    if (t == 0) { g_top1[n] = ri[0]; g_top2[n] = ri2[0]; }
}

// ---------------------------------------------------------------- fp32 rerank + losses (fused; one wave per row)
__global__ __launch_bounds__(256) void rerank_loss_kernel(const float* __restrict__ keys) {
    int n = blockIdx.x * 4 + (threadIdx.x >> 6);
    int lane = threadIdx.x & 63;
    int i1 = g_top1[n], i2 = g_top2[n];
    const float* q  = g_qf      + (size_t)n  * DD;
    const float* k1 = g_keyshat + (size_t)i1 * DD;
    const float* k2 = g_keyshat + (size_t)i2 * DD;
    float s1 = 0.f, s2 = 0.f;
    #pragma unroll
    for (int kk = 0; kk < 8; ++kk) {
        int k = lane + kk * 64;
        float qv = q[k];
        s1 = fmaf(qv, k1[k], s1);
        s2 = fmaf(qv, k2[k], s2);
    }
    #pragma unroll
    for (int off = 1; off < 64; off <<= 1) {
        s1 += __shfl_xor(s1, off);
        s2 += __shfl_xor(s2, off);
    }
    bool sw = (s2 > s1) || (s2 == s1 && i2 < i1);
    int gi = sw ? i2 : i1, ni = sw ? i1 : i2;
    if (lane == 0 && sw) { g_top1[n] = i2; g_top2[n] = i1; }
    const float* kp = keys + (size_t)gi * DD;
    const float* kn = keys + (size_t)ni * DD;
    float comp = 0.f, dpp = 0.f, dnn = 0.f;
    #pragma unroll
    for (int kk = 0; kk < 8; ++kk) {
        int k = lane + kk * 64;
        float qv = q[k];
        float dq = qv - kp[k];
        comp = fmaf(dq, dq, comp);
        float a = dq + 1e-6f;
        dpp = fmaf(a, a, dpp);
        float b2 = qv - kn[k] + 1e-6f;
        dnn = fmaf(b2, b2, dnn);
    }
    #pragma unroll
    for (int off = 1; off < 64; off <<= 1) {
        comp += __shfl_xor(comp, off);
        dpp  += __shfl_xor(dpp,  off);
        dnn  += __shfl_xor(dnn,  off);
    }
    if (lane == 0) {
        float dp = sqrtf(dpp), dn = sqrtf(dnn);
        atomicAdd(&g_bins[n & 63], fmaxf(dp - dn + 1.0f, 0.0f));
        atomicAdd(&g_bins[64 + (n & 63)], comp);
    }
}

// ---------------------------------------------------------------- w_raw + denom + per-slot counts
__global__ __launch_bounds__(256) void wraw_kernel(const float* __restrict__ out) {
    int n = blockIdx.x * 256 + threadIdx.x;
    int gi = g_top1[n];
    float sqv = out[SQ_OFF + (size_t)n * MM + gi];
    float cm = __uint_as_float(g_colmax[gi]) / g_colsum[gi];
    float w = sqv / (cm + 1e-8f);
    g_wraw[n] = w;
    atomicAdd(&g_denom[gi], w);
    atomicAdd(&g_cnt[gi], 1);
}

// ---------------------------------------------------------------- exclusive scan of g_cnt -> g_base (1 block)
__global__ __launch_bounds__(256) void scan_kernel() {
    int t = threadIdx.x;
    __shared__ int chunk[256];
    __shared__ int off[256];
    int loc[8];
    int s = 0;
    #pragma unroll
    for (int i = 0; i < 8; ++i) {
        int idx = t * 8 + i;
        int c = (idx < MM) ? g_cnt[idx] : 0;
        loc[i] = s; s += c;
    }
    chunk[t] = s;
    __syncthreads();
    if (t == 0) {
        int acc = 0;
        for (int i = 0; i < 256; ++i) { off[i] = acc; acc += chunk[i]; }
    }
    __syncthreads();
    #pragma unroll
    for (int i = 0; i < 8; ++i) {
        int idx = t * 8 + i;
        if (idx < MM) g_base[idx] = off[t] + loc[i];
    }
}

// ---------------------------------------------------------------- scatter rows into CSR
__global__ __launch_bounds__(256) void scatter_kernel() {
    int n = blockIdx.x * 256 + threadIdx.x;
    int gi = g_top1[n];
    int pos = atomicAdd(&g_cursor[gi], 1);
    int dst = g_base[gi] + pos;
    g_rows[dst]  = n;
    g_wvals[dst] = g_wraw[n];
}

// ---------------------------------------------------------------- updated_memory via CSR lists
__global__ __launch_bounds__(256) void seg_update_kernel(const float* __restrict__ keys, float* __restrict__ out) {
    int m = blockIdx.x, t = threadIdx.x;
    int start = g_base[m], cnt = g_cnt[m];
    float invd = 1.f / (g_denom[m] + 1e-8f);
    float acc0 = 0.f, acc1 = 0.f;
    for (int i = 0; i < cnt; ++i) {
        int   row = g_rows[start + i];       // block-uniform -> L1 broadcast
        float wgt = g_wvals[start + i] * invd;
        acc0 = fmaf(wgt, g_qf[(size_t)row * DD + t],       acc0);
        acc1 = fmaf(wgt, g_qf[(size_t)row * DD + t + 256], acc1);
    }
    float v0 = acc0 + keys[m * DD + t];
    float v1 = acc1 + keys[m * DD + t + 256];
    __shared__ float red[256];
    red[t] = v0 * v0 + v1 * v1;
    __syncthreads();
    for (int s = 128; s > 0; s >>= 1) { if (t < s) red[t] += red[t + s]; __syncthreads(); }
    float inv = 1.f / fmaxf(sqrtf(red[0]), 1e-12f);
    out[UM_OFF + (size_t)m * DD + t]       = v0 * inv;
    out[UM_OFF + (size_t)m * DD + t + 256] = v1 * inv;
}

// ---------------------------------------------------------------- GEMM2 (MFMA): (SM @ keys)^T via A=keys^T, B=SM
__global__ __launch_bounds__(256, 2) void gemm2_mfma(float* __restrict__ out) {
    __shared__ __attribute__((aligned(16))) u16 Ah[128][64];
    __shared__ __attribute__((aligned(16))) u16 Al[128][64];
    __shared__ __attribute__((aligned(16))) u16 Bh[128][64];
    __shared__ __attribute__((aligned(16))) u16 Bl[128][64];
    int t = threadIdx.x;
    int lane = t & 63, wv = t >> 6;
    int wr = (wv >> 1) << 6, wc = (wv & 1) << 6;
    int l15 = lane & 15, hi = lane >> 4;
    int row0 = blockIdx.x * 128;     // channel dim (0..511)
    int col0 = blockIdx.y * 128;     // query rows n

    f32x4 acc[4][4] = {};
    int lr = lane >> 3, sslot = lane & 7;
    int xs = sslot ^ lr;

    for (int k0 = 0; k0 < KPAD; k0 += 64) {
        #pragma unroll
        for (int p = 0; p < 4; ++p) {
            int r = wv * 8 + lr + p * 32;
            size_t ga = (size_t)(row0 + r) * KPAD + k0 + xs * 8;
            size_t gb = (size_t)(col0 + r) * KPAD + k0 + xs * 8;
            gl_lds16(g_kth + ga, &Ah[p * 32 + wv * 8][0]);
            gl_lds16(g_ktl + ga, &Al[p * 32 + wv * 8][0]);
            gl_lds16(g_smh + gb, &Bh[p * 32 + wv * 8][0]);
            gl_lds16(g_sml + gb, &Bl[p * 32 + wv * 8][0]);
        }
        __syncthreads();
        mfma_block(Ah, Al, Bh, Bl, wr, wc, l15, hi, acc);
        __syncthreads();
    }
    int bq = col0 >> 10;
    #pragma unroll
    for (int i = 0; i < 4; ++i) {
        int chb = row0 + wr + i * 16 + hi * 4;
        #pragma unroll
        for (int j = 0; j < 4; ++j) {
            int n = col0 + wc + j * 16 + l15;
            size_t base = UQ_OFF + ((size_t)(bq * 1024 + 512 + chb)) * 1024 + (n & 1023);
            #pragma unroll
            for (int q = 0; q < 4; ++q)
                out[base + (size_t)q * 1024] = acc[i][j][q];
        }
    }
}

__global__ __launch_bounds__(64) void finalize_kernel(float* __restrict__ out) {
    if (threadIdx.x == 0) {
        float s = 0.f, c = 0.f;
        for (int i = 0; i < 64; ++i) { s += g_bins[i]; c += g_bins[64 + i]; }
        out[SEP_OFF]  = s / (float)NQ;
        out[COMP_OFF] = c / ((float)NQ * (float)DD);
    }
}

// ---------------------------------------------------------------- launch
extern "C" void kernel_launch(void* const* d_in, const int* in_sizes, int n_in,
                              void* d_out, int out_size, void* d_ws, size_t ws_size,
                              hipStream_t stream) {
    const float* query = (const float*)d_in[0];
    const float* keys  = (const float*)d_in[1];
    float* out = (float*)d_out;

    init_kernel<<<dim3(64), dim3(256), 0, stream>>>();
    keys_norm_kernel<<<dim3(MM), dim3(256), 0, stream>>>(keys);
    ktrans_kernel<<<dim3(16, 63), dim3(256), 0, stream>>>(keys);
    qnorm_kernel<<<dim3(512), dim3(256), 0, stream>>>(query, out);
    gemm1_mfma<<<dim3(128, 16), dim3(256), 0, stream>>>(out);
    rowpass_kernel<<<dim3(NQ), dim3(256), 0, stream>>>(out);
    rerank_loss_kernel<<<dim3(NQ / 4), dim3(256), 0, stream>>>(keys);
    wraw_kernel<<<dim3(64), dim3(256), 0, stream>>>(out);
    scan_kernel<<<dim3(1), dim3(256), 0, stream>>>();
    scatter_kernel<<<dim3(64), dim3(256), 0, stream>>>();
    seg_update_kernel<<<dim3(MM), dim3(256), 0, stream>>>(keys, out);
    gemm2_mfma<<<dim3(4, 128), dim3(256), 0, stream>>>(out);
    finalize_kernel<<<dim3(1), dim3(64), 0, stream>>>(out);
}